// Round 2
// baseline (491.153 us; speedup 1.0000x reference)
//
#include <hip/hip_runtime.h>
#include <math.h>

#define LL 2048
#define BB 128
#define HH 300
#define HV4 75   // HH / 4

// Kernel 1: v_t[b][h] = sum_k W[k][h] * hidden[k][b]   (= (W^T @ hidden)^T)
// One block per b; hidden[:,b] staged in LDS; W reads coalesced over h and
// L2-resident (360 KB, reused by all 128 blocks).
__global__ void __launch_bounds__(256) compute_v(const float* __restrict__ W,
                                                 const float* __restrict__ hidden,
                                                 float* __restrict__ v_t) {
    int b   = blockIdx.x;
    int tid = threadIdx.x;
    __shared__ float hcol[HH];
    for (int k = tid; k < HH; k += 256) hcol[k] = hidden[k * BB + b];
    __syncthreads();
    for (int h = tid; h < HH; h += 256) {
        float s = 0.f;
#pragma unroll 4
        for (int k = 0; k < HH; ++k)
            s = fmaf(W[k * HH + h], hcol[k], s);
        v_t[b * HH + h] = s;
    }
}

// Kernel 2 (the 315 MB stream): one wave per (b,l) row.
// Wave id w: b = w>>11, l = w&2047. qv row (l*BB+b) is a contiguous 1200 B
// chunk; energies written [B][L] so the block's 4 writes are 16 B contiguous
// and softmax can read coalesced. Bias omitted: softmax shift-invariant.
__global__ void __launch_bounds__(256) compute_energies(
        const float4* __restrict__ qv4,
        const float4* __restrict__ v4,
        float* __restrict__ energies) {
    int w    = blockIdx.x * 4 + (threadIdx.x >> 6);
    int lane = threadIdx.x & 63;
    int b    = w >> 11;           // w / LL
    int l    = w & (LL - 1);

    const float4* q = qv4 + (size_t)(l * BB + b) * HV4;
    const float4* v = v4  + (size_t)b * HV4;

    float4 a0 = q[lane];
    float4 b0 = v[lane];
    float s = a0.x * b0.x + a0.y * b0.y + a0.z * b0.z + a0.w * b0.w;
    if (lane < HV4 - 64) {        // lanes 0..10 cover elements 64..74
        float4 a1 = q[64 + lane];
        float4 b1 = v[64 + lane];
        s += a1.x * b1.x + a1.y * b1.y + a1.z * b1.z + a1.w * b1.w;
    }
#pragma unroll
    for (int off = 32; off > 0; off >>= 1)
        s += __shfl_down(s, off, 64);
    if (lane == 0)
        energies[b * LL + l] = s;
}

// Kernel 3: softmax over l for each b. One block per b; [B][L] layout so
// all accesses are coalesced float4.
__global__ void __launch_bounds__(256) softmax_rows(
        const float* __restrict__ energies,
        float* __restrict__ out) {
    int b    = blockIdx.x;
    int tid  = threadIdx.x;
    int lane = tid & 63;
    int wave = tid >> 6;

    __shared__ float redm[4];
    __shared__ float reds[4];

    const float4* e4 = (const float4*)(energies + (size_t)b * LL);
    float4 x0 = e4[tid];
    float4 x1 = e4[tid + 256];

    float m = fmaxf(fmaxf(fmaxf(x0.x, x0.y), fmaxf(x0.z, x0.w)),
                    fmaxf(fmaxf(x1.x, x1.y), fmaxf(x1.z, x1.w)));
#pragma unroll
    for (int off = 32; off > 0; off >>= 1)
        m = fmaxf(m, __shfl_down(m, off, 64));
    if (lane == 0) redm[wave] = m;
    __syncthreads();
    m = fmaxf(fmaxf(redm[0], redm[1]), fmaxf(redm[2], redm[3]));

    x0.x = __expf(x0.x - m); x0.y = __expf(x0.y - m);
    x0.z = __expf(x0.z - m); x0.w = __expf(x0.w - m);
    x1.x = __expf(x1.x - m); x1.y = __expf(x1.y - m);
    x1.z = __expf(x1.z - m); x1.w = __expf(x1.w - m);
    float s = (x0.x + x0.y + x0.z + x0.w) + (x1.x + x1.y + x1.z + x1.w);
#pragma unroll
    for (int off = 32; off > 0; off >>= 1)
        s += __shfl_down(s, off, 64);
    if (lane == 0) reds[wave] = s;
    __syncthreads();
    s = reds[0] + reds[1] + reds[2] + reds[3];
    float inv = 1.f / s;

    x0.x *= inv; x0.y *= inv; x0.z *= inv; x0.w *= inv;
    x1.x *= inv; x1.y *= inv; x1.z *= inv; x1.w *= inv;

    float4* o4 = (float4*)(out + (size_t)b * LL);
    o4[tid]       = x0;
    o4[tid + 256] = x1;
}

extern "C" void kernel_launch(void* const* d_in, const int* in_sizes, int n_in,
                              void* d_out, int out_size, void* d_ws, size_t ws_size,
                              hipStream_t stream) {
    const float* hidden = (const float*)d_in[0];   // [H, B]
    const float* qv     = (const float*)d_in[1];   // [L, B, H]
    const float* W      = (const float*)d_in[2];   // [H, H]
    // d_in[3] = bias[H]: softmax-shift-invariant, intentionally unused.
    float* out = (float*)d_out;                    // [B, L]

    float* v_t      = (float*)d_ws;                // BB*HH floats (153600 B, 16B-aligned)
    float* energies = v_t + BB * HH;               // BB*LL floats = 1 MB, [B][L]

    compute_v<<<BB, 256, 0, stream>>>(W, hidden, v_t);
    compute_energies<<<(LL * BB) / 4, 256, 0, stream>>>(
        (const float4*)qv, (const float4*)v_t, energies);
    softmax_rows<<<BB, 256, 0, stream>>>(energies, out);
}

// Round 3
// 476.141 us; speedup vs baseline: 1.0315x; 1.0315x over previous
//
#include <hip/hip_runtime.h>
#include <math.h>

#define LL 2048
#define BB 128
#define HH 300
#define HV4 75   // HH / 4

// Kernel 1: v_t[b][h] = sum_k W[k][h] * hidden[k][b]   (= (W^T @ hidden)^T)
// One block per b; hidden[:,b] staged in LDS; W reads coalesced over h and
// L2-resident (360 KB, reused by all 128 blocks).
__global__ void __launch_bounds__(256) compute_v(const float* __restrict__ W,
                                                 const float* __restrict__ hidden,
                                                 float* __restrict__ v_t) {
    int b   = blockIdx.x;
    int tid = threadIdx.x;
    __shared__ float hcol[HH];
    for (int k = tid; k < HH; k += 256) hcol[k] = hidden[k * BB + b];
    __syncthreads();
    for (int h = tid; h < HH; h += 256) {
        float s = 0.f;
#pragma unroll 4
        for (int k = 0; k < HH; ++k)
            s = fmaf(W[k * HH + h], hcol[k], s);
        v_t[b * HH + h] = s;
    }
}

// Kernel 2 (the 315 MB stream): one wave per row, rows walked in MEMORY ORDER
// (row = l*BB + b) so the whole grid streams qv linearly — each block reads
// 4800 B contiguous, consecutive blocks contiguous (R1's pattern, which
// benched fastest). Energies are written [B][L]: 4 scattered dwords per
// block, absorbed/merged by L2 (1 MB total), off the critical path.
// Bias omitted: adds a per-b constant along the softmax axis -> no-op.
__global__ void __launch_bounds__(256) compute_energies(
        const float4* __restrict__ qv4,
        const float4* __restrict__ v4,
        float* __restrict__ energies) {
    int row  = blockIdx.x * 4 + (threadIdx.x >> 6);  // row = l*BB + b
    int lane = threadIdx.x & 63;
    int b    = row & (BB - 1);
    int l    = row >> 7;                             // row / BB

    const float4* q = qv4 + (size_t)row * HV4;
    const float4* v = v4  + (size_t)b * HV4;

    float4 a0 = q[lane];
    float4 b0 = v[lane];
    float s = a0.x * b0.x + a0.y * b0.y + a0.z * b0.z + a0.w * b0.w;
    if (lane < HV4 - 64) {        // lanes 0..10 cover elements 64..74
        float4 a1 = q[64 + lane];
        float4 b1 = v[64 + lane];
        s += a1.x * b1.x + a1.y * b1.y + a1.z * b1.z + a1.w * b1.w;
    }
#pragma unroll
    for (int off = 32; off > 0; off >>= 1)
        s += __shfl_down(s, off, 64);
    if (lane == 0)
        energies[b * LL + l] = s;                    // [B][L] for coalesced softmax
}

// Kernel 3: softmax over l for each b. One block per b; [B][L] layout so
// all accesses are coalesced float4.
__global__ void __launch_bounds__(256) softmax_rows(
        const float* __restrict__ energies,
        float* __restrict__ out) {
    int b    = blockIdx.x;
    int tid  = threadIdx.x;
    int lane = tid & 63;
    int wave = tid >> 6;

    __shared__ float redm[4];
    __shared__ float reds[4];

    const float4* e4 = (const float4*)(energies + (size_t)b * LL);
    float4 x0 = e4[tid];
    float4 x1 = e4[tid + 256];

    float m = fmaxf(fmaxf(fmaxf(x0.x, x0.y), fmaxf(x0.z, x0.w)),
                    fmaxf(fmaxf(x1.x, x1.y), fmaxf(x1.z, x1.w)));
#pragma unroll
    for (int off = 32; off > 0; off >>= 1)
        m = fmaxf(m, __shfl_down(m, off, 64));
    if (lane == 0) redm[wave] = m;
    __syncthreads();
    m = fmaxf(fmaxf(redm[0], redm[1]), fmaxf(redm[2], redm[3]));

    x0.x = __expf(x0.x - m); x0.y = __expf(x0.y - m);
    x0.z = __expf(x0.z - m); x0.w = __expf(x0.w - m);
    x1.x = __expf(x1.x - m); x1.y = __expf(x1.y - m);
    x1.z = __expf(x1.z - m); x1.w = __expf(x1.w - m);
    float s = (x0.x + x0.y + x0.z + x0.w) + (x1.x + x1.y + x1.z + x1.w);
#pragma unroll
    for (int off = 32; off > 0; off >>= 1)
        s += __shfl_down(s, off, 64);
    if (lane == 0) reds[wave] = s;
    __syncthreads();
    s = reds[0] + reds[1] + reds[2] + reds[3];
    float inv = 1.f / s;

    x0.x *= inv; x0.y *= inv; x0.z *= inv; x0.w *= inv;
    x1.x *= inv; x1.y *= inv; x1.z *= inv; x1.w *= inv;

    float4* o4 = (float4*)(out + (size_t)b * LL);
    o4[tid]       = x0;
    o4[tid + 256] = x1;
}

extern "C" void kernel_launch(void* const* d_in, const int* in_sizes, int n_in,
                              void* d_out, int out_size, void* d_ws, size_t ws_size,
                              hipStream_t stream) {
    const float* hidden = (const float*)d_in[0];   // [H, B]
    const float* qv     = (const float*)d_in[1];   // [L, B, H]
    const float* W      = (const float*)d_in[2];   // [H, H]
    // d_in[3] = bias[H]: softmax-shift-invariant, intentionally unused.
    float* out = (float*)d_out;                    // [B, L]

    float* v_t      = (float*)d_ws;                // BB*HH floats (153600 B, 16B-aligned)
    float* energies = v_t + BB * HH;               // BB*LL floats = 1 MB, [B][L]

    compute_v<<<BB, 256, 0, stream>>>(W, hidden, v_t);
    compute_energies<<<(LL * BB) / 4, 256, 0, stream>>>(
        (const float4*)qv, (const float4*)v_t, energies);
    softmax_rows<<<BB, 256, 0, stream>>>(energies, out);
}